// Round 16
// baseline (278.444 us; speedup 1.0000x reference)
//
#include <hip/hip_runtime.h>
#include <hip/hip_bf16.h>

// NT-Xent (CLIP) loss, N=16384 D=256 fp32 in, 3 fp32 out.
// loss_vu = mean_i( log(sum_j exp(sim_ij)) - sim_ii ), sim = (v̂·û^T)/T
// Logits bounded by 1/T=14.29 -> no max subtraction needed.
//
// Ledger: best K2 = 153us (R12/R14 structure); best TOTAL = 223.06us =
// R12 config (3 dispatches). R13-R17 kept a 4-dispatch structure and
// never beat it: the ~10us/dispatch launch overhead + finalize work is
// the dominant non-K2 term (K1-scatter theory falsified in R17).
//
// R18: revert to R12's proven pieces, FUSE the finalize away (2 dispatches):
//   - K1: R12's normalize (N/8 blocks); diag reduced per-block -> ONE
//     atomicAdd to partials[2]; diagarr deleted. colsum zeroed here.
//   - K2: R12's full-width streaming GEMM verbatim (256 blocks x 64 rows,
//     rows BLOCK-EXCLUSIVE). rowsum -> LDS only: block-local log-sum ->
//     one atomicAdd to partials[0]; rowsum array deleted. colsum per-jt
//     atomics (R12-proven). Tail: threadfence + counter; LAST block
//     reduces colsum logs (coherent atomicAdd(p,0) reads) and writes out.
//   - partials zeroed by 16B hipMemsetAsync (graph-safe, R2-proven).
// Gates: absmax 0 (coherence), total <= 215 (else plateau = R12 config).

#define D_DIM 256

constexpr float INV_T = 1.0f / 0.07f;
constexpr float EXP2_SCALE = 1.44269504088896340736f / 0.07f;  // log2(e)/T

typedef __bf16 bf16x8 __attribute__((ext_vector_type(8)));
typedef float f32x4 __attribute__((ext_vector_type(4)));

// ---------------------------------------------------------------------------
// Kernel 1: L2-normalize fp32 -> bf16 in FRAGMENT-MAJOR layout (R12's
// verified writer). One wave = 2 rows: lane = sub(1)|pos(5); lane handles
// 8 elems [pos*8,+8) of row (blk*8 + wave*2 + sub). Norm-reduce over the
// 32-lane half. Fragment write: row r -> group g=r>>4, slot l15=r&15;
// chunk pos -> ks=pos>>2, quad=pos&3; offset (g*8+ks)*512+(quad*16+l15)*8.
// V' pre-scaled by EXP2_SCALE. Diag: per-wave both-rows sum -> LDS ->
// one atomicAdd(partials[2]) per block. Zeroes colsum.
// ---------------------------------------------------------------------------
__global__ __launch_bounds__(256) void normalize_kernel(
    const float* __restrict__ img, const float* __restrict__ txt,
    __hip_bfloat16* __restrict__ Vf, __hip_bfloat16* __restrict__ Uf,
    float* __restrict__ colsum, float* __restrict__ partials) {
  __shared__ float shd[4];

  const int t = threadIdx.x;
  const int wave = t >> 6;
  const int lane = t & 63;
  const int sub = lane >> 5;   // 0/1: which of the wave's two rows
  const int pos = lane & 31;   // 8-elem chunk index within the row
  const int row = blockIdx.x * 8 + wave * 2 + sub;
  const size_t base = (size_t)row * D_DIM + pos * 8;

  const float4 i0 = *reinterpret_cast<const float4*>(&img[base]);
  const float4 i1 = *reinterpret_cast<const float4*>(&img[base + 4]);
  const float4 t0 = *reinterpret_cast<const float4*>(&txt[base]);
  const float4 t1 = *reinterpret_cast<const float4*>(&txt[base + 4]);

  float a = i0.x * i0.x + i0.y * i0.y + i0.z * i0.z + i0.w * i0.w +
            i1.x * i1.x + i1.y * i1.y + i1.z * i1.z + i1.w * i1.w;
  float b = t0.x * t0.x + t0.y * t0.y + t0.z * t0.z + t0.w * t0.w +
            t1.x * t1.x + t1.y * t1.y + t1.z * t1.z + t1.w * t1.w;
  float d = i0.x * t0.x + i0.y * t0.y + i0.z * t0.z + i0.w * t0.w +
            i1.x * t1.x + i1.y * t1.y + i1.z * t1.z + i1.w * t1.w;
#pragma unroll
  for (int off = 1; off < 32; off <<= 1) {
    a += __shfl_xor(a, off, 64);
    b += __shfl_xor(b, off, 64);
    d += __shfl_xor(d, off, 64);
  }
  const float si = 1.0f / fmaxf(sqrtf(a), 1e-8f);
  const float st = 1.0f / fmaxf(sqrtf(b), 1e-8f);

  const float vs = si * EXP2_SCALE;  // V pre-scaled by log2e/T
  __hip_bfloat16 vb8[8] = {
      __float2bfloat16(i0.x * vs), __float2bfloat16(i0.y * vs),
      __float2bfloat16(i0.z * vs), __float2bfloat16(i0.w * vs),
      __float2bfloat16(i1.x * vs), __float2bfloat16(i1.y * vs),
      __float2bfloat16(i1.z * vs), __float2bfloat16(i1.w * vs)};
  __hip_bfloat16 ub8[8] = {
      __float2bfloat16(t0.x * st), __float2bfloat16(t0.y * st),
      __float2bfloat16(t0.z * st), __float2bfloat16(t0.w * st),
      __float2bfloat16(t1.x * st), __float2bfloat16(t1.y * st),
      __float2bfloat16(t1.z * st), __float2bfloat16(t1.w * st)};

  const int g = row >> 4, l15r = row & 15;
  const int ks = pos >> 2, quad = pos & 3;
  const size_t foff = (size_t)(g * 8 + ks) * 512 + (quad * 16 + l15r) * 8;
  *reinterpret_cast<uint4*>(&Vf[foff]) = *reinterpret_cast<uint4*>(vb8);
  *reinterpret_cast<uint4*>(&Uf[foff]) = *reinterpret_cast<uint4*>(ub8);

  // diag v̂_i·û_i (unscaled): per-half value, combine the wave's 2 rows.
  float dn = d * si * st;
  dn += __shfl_xor(dn, 32, 64);
  if (lane == 0) shd[wave] = dn;
  __syncthreads();
  if (t == 0) atomicAdd(&partials[2], shd[0] + shd[1] + shd[2] + shd[3]);

  if (t < 8) colsum[blockIdx.x * 8 + t] = 0.0f;
}

// ---------------------------------------------------------------------------
// Kernel 2: barrier-free streaming MFMA GEMM + online exp2 sums + fused
// finalize. R12's proven loop verbatim: block = 64 rows (groups 4b..4b+3,
// BLOCK-EXCLUSIVE) x all N cols; 8 waves; wave w covers cols
// [jt*512 + w*64, +64) of each 512-col j-tile (njt=32). A a[4][8] (128
// VGPR) resident. B depth-2 ring bb[2][4]; issue load(ks+1), SB(0) pin,
// consume bank ks&1; ks=7 prefetches next jt's ks0 (epilogue-covered).
// Tail: rowsum -> LDS rowbuf -> block log-sum -> atomicAdd(partials[0]);
// threadfence + counter (partials[3]); last block reduces colsum logs
// via coherent atomicAdd(p,0) reads and writes out[3].
// acc layout (verified): row = mi*16 + quad*4 + r, col = ni*16 + l15.
// ---------------------------------------------------------------------------
__global__ __launch_bounds__(512, 2) void gemm_lse_kernel(
    const __hip_bfloat16* __restrict__ Vf, const __hip_bfloat16* __restrict__ Uf,
    float* __restrict__ colsum, float* __restrict__ partials,
    float* __restrict__ out, int n) {
  __shared__ float rowbuf[64];
  __shared__ float shred[8];
  __shared__ unsigned s_last;

  const int tid = threadIdx.x;
  const int lane = tid & 63;
  const int w = tid >> 6;        // 0..7
  const int quad = lane >> 4;
  const int l15 = lane & 15;
  const int b = blockIdx.x;
  const int njt = n >> 9;        // j-tiles of 512 cols (32)

  // A fragments for rows [b*64, +64): groups 4b..4b+3, all K, once.
  bf16x8 a[4][8];
#pragma unroll
  for (int mi = 0; mi < 4; ++mi)
#pragma unroll
    for (int ks = 0; ks < 8; ++ks)
      a[mi][ks] = *reinterpret_cast<const bf16x8*>(
          Vf + (size_t)((4 * b + mi) * 8 + ks) * 512 + lane * 8);

  float rs[4][4] = {};  // rowsum partials (mi, r), all jt

  // B base for this wave: col group = jt*32 + w*4 + ni; frag at
  // (group*8 + ks)*512 + lane*8.
  const __hip_bfloat16* Ub = Uf + (size_t)(w * 4) * 8 * 512 + lane * 8;

  // Depth-2 ring. Prologue: jt0 ks0 -> bank 0.
  bf16x8 bb[2][4];
#pragma unroll
  for (int ni = 0; ni < 4; ++ni)
    bb[0][ni] = *reinterpret_cast<const bf16x8*>(Ub + (size_t)(ni * 8) * 512);

  for (int jt = 0; jt < njt; ++jt) {
    const size_t jb = (size_t)jt * (32 * 8 * 512);
    const size_t jbn = (jt < njt - 1) ? jb + 32 * 8 * 512 : 0;  // wrap: jt0
    f32x4 acc[4][4] = {};

#pragma unroll
    for (int ks = 0; ks < 8; ++ks) {
      // issue load for step ks+1 into the other bank (free since ks-1)
      {
        const size_t pjb = (ks < 7) ? jb : jbn;
        const int pks = (ks < 7) ? ks + 1 : 0;
#pragma unroll
        for (int ni = 0; ni < 4; ++ni)
          bb[(ks + 1) & 1][ni] = *reinterpret_cast<const bf16x8*>(
              Ub + pjb + (size_t)(ni * 8 + pks) * 512);
        __builtin_amdgcn_sched_barrier(0);
      }
      // consume bank ks&1 (waitcnt for its step-(ks-1) loads)
#pragma unroll
      for (int mi = 0; mi < 4; ++mi)
#pragma unroll
        for (int ni = 0; ni < 4; ++ni)
          acc[mi][ni] = __builtin_amdgcn_mfma_f32_16x16x32_bf16(
              a[mi][ks], bb[ks & 1][ni], acc[mi][ni], 0, 0, 0);
    }

    // per-jt epilogue: exp2, rowsum regs, colsum atomics (cols wave-excl.)
    // -- also the latency cover for the next jt's ks0 prefetch.
    float cs0 = 0.f, cs1 = 0.f, cs2 = 0.f, cs3 = 0.f;
#pragma unroll
    for (int mi = 0; mi < 4; ++mi)
#pragma unroll
      for (int r = 0; r < 4; ++r) {
        const float e0 = __builtin_amdgcn_exp2f(acc[mi][0][r]);
        const float e1 = __builtin_amdgcn_exp2f(acc[mi][1][r]);
        const float e2 = __builtin_amdgcn_exp2f(acc[mi][2][r]);
        const float e3 = __builtin_amdgcn_exp2f(acc[mi][3][r]);
        rs[mi][r] += e0 + e1 + e2 + e3;
        cs0 += e0; cs1 += e1; cs2 += e2; cs3 += e3;
      }
    float csa[4] = {cs0, cs1, cs2, cs3};
#pragma unroll
    for (int ni = 0; ni < 4; ++ni) {
      float c = csa[ni];
      c += __shfl_xor(c, 16, 64);
      c += __shfl_xor(c, 32, 64);
      if (lane < 16)
        atomicAdd(&colsum[jt * 512 + w * 64 + ni * 16 + l15], c);
    }
  }

  // ---- fused rowsum finalize: rows are block-exclusive ----
  if (tid < 64) rowbuf[tid] = 0.0f;
  __syncthreads();
#pragma unroll
  for (int mi = 0; mi < 4; ++mi)
#pragma unroll
    for (int r = 0; r < 4; ++r) {
      float v = rs[mi][r];
      v += __shfl_xor(v, 1, 64);
      v += __shfl_xor(v, 2, 64);
      v += __shfl_xor(v, 4, 64);
      v += __shfl_xor(v, 8, 64);
      if (l15 == 0)
        atomicAdd(&rowbuf[mi * 16 + quad * 4 + r], v);  // LDS atomic
    }
  __syncthreads();
  if (tid < 64) {  // wave 0: block's log-sum of its 64 complete rowsums
    float lg = __logf(rowbuf[tid]);
#pragma unroll
    for (int off = 1; off < 64; off <<= 1) lg += __shfl_xor(lg, off, 64);
    if (tid == 0) atomicAdd(&partials[0], lg);
  }

  // ---- last-block colsum finalize ----
  __threadfence();  // colsum atomics + partials[0] visible before counter
  if (tid == 0) {
    const unsigned old = atomicAdd((unsigned*)(partials + 3), 1u);
    s_last = (old == (unsigned)(gridDim.x - 1)) ? 1u : 0u;
  }
  __syncthreads();
  if (s_last) {
    float sc = 0.0f;
    for (int i = tid; i < n; i += 512)
      sc += __logf(atomicAdd(&colsum[i], 0.0f));  // coherent read
#pragma unroll
    for (int off = 1; off < 64; off <<= 1) sc += __shfl_xor(sc, off, 64);
    if (lane == 0) shred[w] = sc;
    __syncthreads();
    if (tid == 0) {
      float tc = 0.0f;
#pragma unroll
      for (int i = 0; i < 8; ++i) tc += shred[i];
      const float sr = atomicAdd(&partials[0], 0.0f);  // all blocks done
      const float td = atomicAdd(&partials[2], 0.0f);  // from K1
      const float invN = 1.0f / (float)n;
      const float dm = td * INV_T * invN;  // mean diag logit
      const float lvu = sr * invN - dm;
      const float luv = tc * invN - dm;
      out[0] = 0.5f * lvu + 0.5f * luv;  // WEIGHT = 0.5
      out[1] = lvu;
      out[2] = luv;
    }
  }
}

extern "C" void kernel_launch(void* const* d_in, const int* in_sizes, int n_in,
                              void* d_out, int out_size, void* d_ws, size_t ws_size,
                              hipStream_t stream) {
  const float* img = (const float*)d_in[0];
  const float* txt = (const float*)d_in[1];
  float* out = (float*)d_out;
  const int N = in_sizes[0] / D_DIM;  // 16384

  char* ws = (char*)d_ws;
  __hip_bfloat16* Vf = (__hip_bfloat16*)ws;                             // 8MB
  __hip_bfloat16* Uf = (__hip_bfloat16*)(ws + (size_t)N * D_DIM * 2);   // 8MB
  float* colsum = (float*)(ws + (size_t)N * D_DIM * 4);
  float* partials = colsum + N;  // [0]=rowlogs [1]=unused [2]=diag [3]=counter

  // zero partials (incl. counter) before K1's diag atomics (race-free).
  hipMemsetAsync(partials, 0, 4 * sizeof(float), stream);

  normalize_kernel<<<N / 8, 256, 0, stream>>>(img, txt, Vf, Uf, colsum,
                                              partials);

  gemm_lse_kernel<<<N / 64, 512, 0, stream>>>(Vf, Uf, colsum, partials, out,
                                              N);
}